// Round 10
// baseline (397.613 us; speedup 1.0000x reference)
//
#include <hip/hip_runtime.h>
#include <stdint.h>

typedef uint32_t u32;
typedef uint16_t u16;

static constexpr int M_DIM = 8192;
static constexpr int N_DIM = 1024;
static constexpr int K_DIM = 4096;

// ws layout: H row-major fp16 [8192][4096] (64 MiB) + Wt frag-major (8 MiB)
static constexpr size_t H_BYTES  = (size_t)M_DIM * K_DIM * 2;   // 64 MiB
static constexpr size_t FRAG_U16 = 512;
static constexpr size_t WT_BYTES = 64ull * 128 * FRAG_U16 * 2;  // 8 MiB
static constexpr size_t WS_NEEDED = H_BYTES + WT_BYTES;         // 72 MiB

typedef __attribute__((ext_vector_type(8))) _Float16 half8;  // MFMA A/B frag (4 VGPRs)
typedef __attribute__((ext_vector_type(4))) float f32x4;     // MFMA C/D frag

__device__ __forceinline__ u32 pack2(float a, float b) {
  union { _Float16 h[2]; u32 u; } p;
  p.h[0] = (_Float16)a;   // v_cvt_f16_f32, RNE
  p.h[1] = (_Float16)b;
  return p.u;
}

// GELU via Abramowitz-Stegun 7.1.26 erf (|err| <= 1.5e-7) + dropout keep-mask * 1/(1-0.1).
__device__ __forceinline__ float gelu_drop(float x, u32 keep) {
  float ax = fabsf(x);
  float z  = ax * 0.70710678f;
  float t  = __builtin_amdgcn_rcpf(fmaf(0.3275911f, z, 1.0f));
  float poly = fmaf(fmaf(fmaf(fmaf(1.061405429f, t, -1.453152027f),
                              t, 1.421413741f),
                         t, -0.284496736f),
                    t, 0.254829592f) * t;
  float e   = exp2f(z * z * -1.44269504f);    // exp(-z^2)
  float erf = fmaf(-poly, e, 1.0f);           // erf(|x|/sqrt(2)) in [0,1)
  float g   = 0.5f * x * (1.0f + copysignf(erf, x));
  return keep ? g * 1.1111112f : 0.0f;
}

__device__ __forceinline__ void async_cp16(const void* g, void* l) {
  __builtin_amdgcn_global_load_lds((__attribute__((address_space(1))) u32*)g,
                                   (__attribute__((address_space(3))) u32*)l,
                                   16, 0, 0);
}

// ---------------- pass 1 (merged): W prepack + X gelu-pack via global_load_lds DMA ring ----------------
// blocks [0, WPACK_BLOCKS): verified W prepack (17 MB f32 -> 8 MB fp16 frag-major).
// blocks [WPACK_BLOCKS, +PACKX_BLOCKS): X/Mask loads through the DMA path:
//   4-slot LDS ring, 8 KB/slot (X 4 KB + Mask 4 KB for 256 granules). Each wave stages its
//   own lanes' bytes (LDS dest = uniform base + lane*16) and reads them back after an EXACT
//   counted vmcnt (FIFO ledger incl. the interleaved H stores) -- no barriers anywhere.
static constexpr int W_PAIRS = 64 * 64;
static constexpr int WPACK_BLOCKS = W_PAIRS / 4;    // 1024
static constexpr int PACKX_BLOCKS = 2048;
static constexpr int PACK_CHUNKS = 16;              // 16 chunks x 256 granules per block

__global__ __launch_bounds__(256)
void pack_kernel(const float* __restrict__ X, const int* __restrict__ Mask,
                 const float* __restrict__ W, u16* __restrict__ H, u16* __restrict__ Wt) {
  __shared__ __attribute__((aligned(16))) char S[4][8192];  // ring: 4 x (X 4K + M 4K)

  if (blockIdx.x < WPACK_BLOCKS) {
    // ---- W prepack (verified R3-R9, unchanged) ----
    const int l     = threadIdx.x & 63;
    const int pj    = blockIdx.x * 4 + (threadIdx.x >> 6);
    const int row16 = l & 15;
    const int kof   = (l >> 4) << 4;
    const int fsub  = kof >> 5;
    const int q0    = (kof & 31) >> 3;
    const int nb = pj >> 6, kp = pj & 63;
    const float* wp = W + (size_t)(nb * 16 + row16) * K_DIM + kp * 64 + kof;
    float4 w0 = *(const float4*)(wp + 0);
    float4 w1 = *(const float4*)(wp + 4);
    float4 w2 = *(const float4*)(wp + 8);
    float4 w3 = *(const float4*)(wp + 12);
    const int f = kp * 2 + fsub;
    u16* dst = Wt + (size_t)(nb * 128 + f) * FRAG_U16 + (size_t)(row16 + 16 * q0) * 8;
    *(uint4*)(dst)       = make_uint4(pack2(w0.x, w0.y), pack2(w0.z, w0.w),
                                      pack2(w1.x, w1.y), pack2(w1.z, w1.w));
    *(uint4*)(dst + 128) = make_uint4(pack2(w2.x, w2.y), pack2(w2.z, w2.w),
                                      pack2(w3.x, w3.y), pack2(w3.z, w3.w));
    return;
  }

  const int tid = threadIdx.x;
  const size_t blockG = (size_t)(blockIdx.x - WPACK_BLOCKS) * (PACK_CHUNKS * 256);
  const float4* Xv = (const float4*)X;
  const uint4*  Mv = (const uint4*)Mask;

  auto stage = [&](int c) {
    const int slot = c & 3;
    const size_t g = blockG + (size_t)c * 256 + tid;     // per-lane granule
    async_cp16(Xv + g, (char*)S + slot * 8192 + tid * 16);
    async_cp16(Mv + g, (char*)S + slot * 8192 + 4096 + tid * 16);
  };

  // prologue: 3 chunks in flight
  stage(0);
  stage(1);
  stage(2);

#pragma unroll
  for (int c = 0; c < PACK_CHUNKS; ++c) {
    if (c + 3 < PACK_CHUNKS) stage(c + 3);
    // exact FIFO ledger: items newer than L_c^M at the wait point
    //   c=0:6  c=1:7  c=2:8  c in [3,12]:9  c=13:7  c=14:5  c=15:3
    const int nv = (c < 1) ? 6 : (c < 2) ? 7 : (c < 3) ? 8
                 : (c < 13) ? 9 : (c == 13) ? 7 : (c == 14) ? 5 : 3;
    switch (nv) {
      case 3: asm volatile("s_waitcnt vmcnt(3)" ::: "memory"); break;
      case 5: asm volatile("s_waitcnt vmcnt(5)" ::: "memory"); break;
      case 6: asm volatile("s_waitcnt vmcnt(6)" ::: "memory"); break;
      case 7: asm volatile("s_waitcnt vmcnt(7)" ::: "memory"); break;
      case 8: asm volatile("s_waitcnt vmcnt(8)" ::: "memory"); break;
      default: asm volatile("s_waitcnt vmcnt(9)" ::: "memory"); break;
    }
    __builtin_amdgcn_sched_barrier(0);
    const int slot = c & 3;
    const char* sb = (const char*)S + slot * 8192;
    float4 xv = *(const float4*)(sb + tid * 16);
    uint4  mv = *(const uint4*)(sb + 4096 + tid * 16);
    const u32 lo = pack2(gelu_drop(xv.x, mv.x), gelu_drop(xv.y, mv.y));
    const u32 hi = pack2(gelu_drop(xv.z, mv.z), gelu_drop(xv.w, mv.w));
    *(uint2*)(H + (blockG + (size_t)c * 256 + tid) * 4) = make_uint2(lo, hi);
  }
}

// ---------------- pass 2: 128x128 GEMM, double-buffered, XCD-co-located H stripes ----------------
// (verified R8: ~99 us — UNCHANGED, control)
__global__ __launch_bounds__(256, 2)
void gemm_kernel(const u16* __restrict__ H, const u16* __restrict__ Wt,
                 const float* __restrict__ Bias, float* __restrict__ Out) {
  __shared__ __attribute__((aligned(16))) u16 Asl[2][8192];  // 2 x 16 KiB
  __shared__ __attribute__((aligned(16))) u16 Bsl[2][8192];  // 2 x 16 KiB

  const int tid  = threadIdx.x;
  const int lane = tid & 63;
  const int wv   = tid >> 6;   // 0..3
  const int wr   = wv >> 1;    // row half (64 rows)
  const int wc   = wv & 1;     // col half (64 cols)

  const int x  = blockIdx.x & 7;        // XCD under round-robin dispatch
  const int j  = blockIdx.x >> 3;       // 0..63
  const int bm = x * 8 + (j & 7);       // 0..63 : XCD x owns 8 contiguous stripes
  const int bn = j >> 3;                // 0..7
  const int m0 = bm * 128;
  const int n0 = bn * 128;

  const char* Hc = (const char*)H;
  const char* Wc = (const char*)Wt;

  // staging source offsets (4 x 16 B per thread each for A and B) [verified R7-R9]
  size_t aSrc[4], bSrc[4];
#pragma unroll
  for (int p = 0; p < 4; ++p) {
    const int s = tid + 256 * p;
    const int row = s >> 3, ch = s & 7;
    // pre-swizzled source chunk: ch' = ch ^ (row&7); LDS dest stays linear (s*16)
    aSrc[p] = (size_t)(m0 + row) * (K_DIM * 2) + (size_t)(((u32)ch ^ ((u32)row & 7u)) * 16);
    const int f = s >> 6;  // 0..15: nf = f>>1, kk = f&1
    bSrc[p] = ((size_t)((bn * 8 + (f >> 1)) * 128 + (f & 1))) * 1024 + (size_t)(s & 63) * 16;
  }

  auto stage = [&](int ks, int buf) {
    const size_t ka = (size_t)ks * 128;    // 64 k * 2 B per step
    const size_t kb = (size_t)ks * 2048;   // 2 kt-frags per step
#pragma unroll
    for (int p = 0; p < 4; ++p)
      async_cp16(Hc + aSrc[p] + ka, (char*)Asl[buf] + (size_t)(tid + 256 * p) * 16);
#pragma unroll
    for (int p = 0; p < 4; ++p)
      async_cp16(Wc + bSrc[p] + kb, (char*)Bsl[buf] + (size_t)(tid + 256 * p) * 16);
  };

  f32x4 acc[4][4];
#pragma unroll
  for (int i = 0; i < 4; ++i)
#pragma unroll
    for (int jj = 0; jj < 4; ++jj)
      acc[i][jj] = (f32x4){0.f, 0.f, 0.f, 0.f};

  // prologue: stage ks=0 into buf 0
  stage(0, 0);
  __syncthreads();

  int buf = 0;
#pragma unroll 1
  for (int ks = 0; ks < 64; ++ks) {
    if (ks + 1 < 64) stage(ks + 1, buf ^ 1);   // prefetch while computing

    const char* ac = (const char*)Asl[buf];
    const char* bc = (const char*)Bsl[buf];
#pragma unroll
    for (int kk = 0; kk < 2; ++kk) {
      half8 ar[4], br[4];
#pragma unroll
      for (int i = 0; i < 4; ++i) {
        const int row = wr * 64 + i * 16 + (lane & 15);
        const u32 ch = ((u32)(kk * 4 + (lane >> 4))) ^ ((u32)lane & 7u);
        ar[i] = *(const half8*)(ac + (size_t)row * 128 + ch * 16);
      }
#pragma unroll
      for (int jj = 0; jj < 4; ++jj)
        br[jj] = *(const half8*)(bc + (size_t)(((wc * 4 + jj) * 2 + kk) * 1024) + lane * 16);
#pragma unroll
      for (int i = 0; i < 4; ++i)
#pragma unroll
        for (int jj = 0; jj < 4; ++jj)
          acc[i][jj] = __builtin_amdgcn_mfma_f32_16x16x32_f16(ar[i], br[jj], acc[i][jj], 0, 0, 0);
    }
    __syncthreads();   // staging of ks+1 drained (compiler vmcnt) + all reads of buf done
    buf ^= 1;
  }

  // ---- epilogue: C/D layout col = lane&15, row = (lane>>4)*4 + reg [verified R0-R9] ----
  const int fr = lane & 15;
  const int rq = (lane >> 4) << 2;
  float bv[4];
#pragma unroll
  for (int jj = 0; jj < 4; ++jj)
    bv[jj] = Bias[n0 + wc * 64 + jj * 16 + fr];
#pragma unroll
  for (int i = 0; i < 4; ++i) {
    const int row0 = m0 + wr * 64 + i * 16 + rq;
#pragma unroll
    for (int jj = 0; jj < 4; ++jj) {
      const int col = n0 + wc * 64 + jj * 16 + fr;
#pragma unroll
      for (int r = 0; r < 4; ++r)
        Out[(size_t)(row0 + r) * N_DIM + col] = acc[i][jj][r] + bv[jj];
    }
  }
}

// ---------------- fallback: verified R3 fused kernel (only if ws too small) ----------------
static constexpr int A_STRIDE = 40;

__global__ __launch_bounds__(256, 2)
void fused_fallback_kernel(const float* __restrict__ X, const float* __restrict__ W,
                           const float* __restrict__ Bias, const int* __restrict__ Mask,
                           float* __restrict__ Out) {
  __shared__ __attribute__((aligned(16))) _Float16 As[128 * A_STRIDE];
  __shared__ __attribute__((aligned(16))) _Float16 Bs[128 * 32];

  const int tid  = threadIdx.x;
  const int lane = tid & 63;
  const int wv   = tid >> 6;
  const int wr   = wv >> 1;
  const int wc   = wv & 1;
  const int bm = blockIdx.x & 63;
  const int bn = blockIdx.x >> 6;
  const int m0 = bm * 128;
  const int n0 = bn * 128;

  const int a_m = tid >> 1;
  const int a_k = (tid & 1) << 4;
  const float* xptr = X    + (size_t)(m0 + a_m) * K_DIM + a_k;
  const int*   mptr = Mask + (size_t)(m0 + a_m) * K_DIM + a_k;
  _Float16* a_lds = &As[a_m * A_STRIDE + a_k];

  const int i0 = tid, i1 = tid + 256;
  const float* wp0 = W + (size_t)(n0 + (i0 >> 2)) * K_DIM + ((i0 & 3) << 3);
  const float* wp1 = W + (size_t)(n0 + (i1 >> 2)) * K_DIM + ((i1 & 3) << 3);
  _Float16* bl0 = &Bs[i0 * 8];
  _Float16* bl1 = &Bs[i1 * 8];

  f32x4 acc[4][4];
#pragma unroll
  for (int i = 0; i < 4; ++i)
#pragma unroll
    for (int j = 0; j < 4; ++j)
      acc[i][j] = (f32x4){0.f, 0.f, 0.f, 0.f};

  float4 xf0 = *(const float4*)(xptr +  0);
  float4 xf1 = *(const float4*)(xptr +  4);
  float4 xf2 = *(const float4*)(xptr +  8);
  float4 xf3 = *(const float4*)(xptr + 12);
  uint4  mr0 = *(const uint4*)(mptr +  0);
  uint4  mr1 = *(const uint4*)(mptr +  4);
  uint4  mr2 = *(const uint4*)(mptr +  8);
  uint4  mr3 = *(const uint4*)(mptr + 12);
  float4 wf0 = *(const float4*)(wp0 + 0);
  float4 wf1 = *(const float4*)(wp0 + 4);
  float4 wf2 = *(const float4*)(wp1 + 0);
  float4 wf3 = *(const float4*)(wp1 + 4);

#pragma unroll 1
  for (int kt = 0; kt < 128; ++kt) {
    {
      float xs[16] = {xf0.x, xf0.y, xf0.z, xf0.w, xf1.x, xf1.y, xf1.z, xf1.w,
                      xf2.x, xf2.y, xf2.z, xf2.w, xf3.x, xf3.y, xf3.z, xf3.w};
      u32 mk[16]   = {mr0.x, mr0.y, mr0.z, mr0.w, mr1.x, mr1.y, mr1.z, mr1.w,
                      mr2.x, mr2.y, mr2.z, mr2.w, mr3.x, mr3.y, mr3.z, mr3.w};
      u32 ow[8];
#pragma unroll
      for (int e = 0; e < 8; ++e)
        ow[e] = pack2(gelu_drop(xs[2 * e], mk[2 * e]), gelu_drop(xs[2 * e + 1], mk[2 * e + 1]));
      ((uint4*)a_lds)[0] = make_uint4(ow[0], ow[1], ow[2], ow[3]);
      ((uint4*)a_lds)[1] = make_uint4(ow[4], ow[5], ow[6], ow[7]);
    }
    {
      *(uint4*)bl0 = make_uint4(pack2(wf0.x, wf0.y), pack2(wf0.z, wf0.w),
                                pack2(wf1.x, wf1.y), pack2(wf1.z, wf1.w));
      *(uint4*)bl1 = make_uint4(pack2(wf2.x, wf2.y), pack2(wf2.z, wf2.w),
                                pack2(wf3.x, wf3.y), pack2(wf3.z, wf3.w));
    }
    __syncthreads();

    if (kt + 1 < 128) {
      xptr += 32; mptr += 32; wp0 += 32; wp1 += 32;
      xf0 = *(const float4*)(xptr +  0);
      xf1 = *(const float4*)(xptr +  4);
      xf2 = *(const float4*)(xptr +  8);
      xf3 = *(const float4*)(xptr + 12);
      mr0 = *(const uint4*)(mptr +  0);
      mr1 = *(const uint4*)(mptr +  4);
      mr2 = *(const uint4*)(mptr +  8);
      mr3 = *(const uint4*)(mptr + 12);
      wf0 = *(const float4*)(wp0 + 0);
      wf1 = *(const float4*)(wp0 + 4);
      wf2 = *(const float4*)(wp1 + 0);
      wf3 = *(const float4*)(wp1 + 4);
    }

    {
      const int fr2 = lane & 15;
      const int fk2 = (lane >> 4) << 3;
      half8 ar[4], br[4];
#pragma unroll
      for (int i = 0; i < 4; ++i)
        ar[i] = *(const half8*)&As[(wr * 64 + i * 16 + fr2) * A_STRIDE + fk2];
#pragma unroll
      for (int j = 0; j < 4; ++j)
        br[j] = *(const half8*)&Bs[(wc * 64 + j * 16 + fr2) * 32 + fk2];
#pragma unroll
      for (int i = 0; i < 4; ++i)
#pragma unroll
        for (int j = 0; j < 4; ++j)
          acc[i][j] = __builtin_amdgcn_mfma_f32_16x16x32_f16(ar[i], br[j], acc[i][j], 0, 0, 0);
    }
    __syncthreads();
  }

  const int fr = lane & 15;
  const int rq = (lane >> 4) << 2;
  float bv[4];
#pragma unroll
  for (int j = 0; j < 4; ++j)
    bv[j] = Bias[n0 + wc * 64 + j * 16 + fr];
#pragma unroll
  for (int i = 0; i < 4; ++i) {
    const int row0 = m0 + wr * 64 + i * 16 + rq;
#pragma unroll
    for (int j = 0; j < 4; ++j) {
      const int col = n0 + wc * 64 + j * 16 + fr;
#pragma unroll
      for (int r = 0; r < 4; ++r)
        Out[(size_t)(row0 + r) * N_DIM + col] = acc[i][j][r] + bv[j];
    }
  }
}

extern "C" void kernel_launch(void* const* d_in, const int* in_sizes, int n_in,
                              void* d_out, int out_size, void* d_ws, size_t ws_size,
                              hipStream_t stream) {
  const float* X    = (const float*)d_in[0];   // x (8192x4096), fp16 canonicalized to f32
  const float* W    = (const float*)d_in[1];   // weight (1024x4096) f32, K-contiguous
  const float* Bias = (const float*)d_in[2];   // bias (1024) f32
  const int*   Mk   = (const int*)d_in[3];     // keep-mask int32 0/1
  float* Out = (float*)d_out;                  // y (8192x1024) f32

  if (ws_size >= WS_NEEDED) {
    u16* H  = (u16*)d_ws;
    u16* Wt = (u16*)((char*)d_ws + H_BYTES);
    pack_kernel<<<WPACK_BLOCKS + PACKX_BLOCKS, 256, 0, stream>>>(X, Mk, W, H, Wt);
    gemm_kernel<<<(M_DIM / 128) * (N_DIM / 128), 256, 0, stream>>>(H, Wt, Bias, Out);  // 512 blocks
  } else {
    fused_fallback_kernel<<<64 * 8, 256, 0, stream>>>(X, W, Bias, Mk, Out);
  }
}

// Round 11
// 375.399 us; speedup vs baseline: 1.0592x; 1.0592x over previous
//
#include <hip/hip_runtime.h>
#include <stdint.h>

typedef uint32_t u32;
typedef uint16_t u16;

static constexpr int M_DIM = 8192;
static constexpr int N_DIM = 1024;
static constexpr int K_DIM = 4096;

// Wt frag-major: [nb16(64)][kt32(128)] frags of 1 KiB; frag lane l = kq*16+row16 holds 16 B.
static constexpr size_t FRAG_U16 = 512;
static constexpr size_t WT_BYTES = 64ull * 128 * FRAG_U16 * 2;  // 8 MiB
static constexpr size_t WS_NEEDED = WT_BYTES;

typedef __attribute__((ext_vector_type(8))) _Float16 half8;  // MFMA A/B frag (4 VGPRs)
typedef __attribute__((ext_vector_type(4))) float f32x4;     // MFMA C/D frag

__device__ __forceinline__ u32 pack2(float a, float b) {
  union { _Float16 h[2]; u32 u; } p;
  p.h[0] = (_Float16)a;   // v_cvt_f16_f32, RNE
  p.h[1] = (_Float16)b;
  return p.u;
}

// GELU via Abramowitz-Stegun 7.1.26 erf (|err| <= 1.5e-7) + dropout keep-mask * 1/(1-0.1).
__device__ __forceinline__ float gelu_drop(float x, u32 keep) {
  float ax = fabsf(x);
  float z  = ax * 0.70710678f;
  float t  = __builtin_amdgcn_rcpf(fmaf(0.3275911f, z, 1.0f));
  float poly = fmaf(fmaf(fmaf(fmaf(1.061405429f, t, -1.453152027f),
                              t, 1.421413741f),
                         t, -0.284496736f),
                    t, 0.254829592f) * t;
  float e   = exp2f(z * z * -1.44269504f);    // exp(-z^2)
  float erf = fmaf(-poly, e, 1.0f);           // erf(|x|/sqrt(2)) in [0,1)
  float g   = 0.5f * x * (1.0f + copysignf(erf, x));
  return keep ? g * 1.1111112f : 0.0f;
}

// ---------------- W prepack (verified R3-R10): 17 MB f32 -> 8 MB fp16 frag-major ----------------
static constexpr int W_PAIRS = 64 * 64;          // nb(64) x kp(64)
static constexpr int WPACK_BLOCKS = W_PAIRS / 4; // 1024

__global__ __launch_bounds__(256)
void wpack_kernel(const float* __restrict__ W, u16* __restrict__ Wt) {
  const int l     = threadIdx.x & 63;
  const int pj    = blockIdx.x * 4 + (threadIdx.x >> 6);
  const int row16 = l & 15;
  const int kof   = (l >> 4) << 4;          // 0,16,32,48 within the 64-k pair
  const int fsub  = kof >> 5;               // 0 or 1
  const int q0    = (kof & 31) >> 3;        // 0 or 2

  const int nb = pj >> 6, kp = pj & 63;
  const float* wp = W + (size_t)(nb * 16 + row16) * K_DIM + kp * 64 + kof;
  float4 w0 = *(const float4*)(wp + 0);
  float4 w1 = *(const float4*)(wp + 4);
  float4 w2 = *(const float4*)(wp + 8);
  float4 w3 = *(const float4*)(wp + 12);
  const int f = kp * 2 + fsub;
  u16* dst = Wt + (size_t)(nb * 128 + f) * FRAG_U16 + (size_t)(row16 + 16 * q0) * 8;
  *(uint4*)(dst)       = make_uint4(pack2(w0.x, w0.y), pack2(w0.z, w0.w),
                                    pack2(w1.x, w1.y), pack2(w1.z, w1.w));
  *(uint4*)(dst + 128) = make_uint4(pack2(w2.x, w2.y), pack2(w2.z, w2.w),
                                    pack2(w3.x, w3.y), pack2(w3.z, w3.w));
}

// ---------------- fused GELU+dropout+GEMM: BM=64 x BN=512, SAME-STRIPE XCD CO-LOCATION ----------------
// R5's verified machinery (passed correctness), ONE change: the bid->tile mapping.
//   xcd = bid&7 owns row stripes [xcd*16, xcd*16+16); col halves of a stripe are bids 16 apart
//   (same xcd, co-resident 1 block/CU) -> the 2nd X/Mask reader is L2-warm (R5 made it cold on
//   another XCD = 2 MB cold/CU = 205 us). B halves (4 MB) are L2-resident across their 16
//   same-XCD readers. Cold bytes chip-wide ~ X+M 268 MB once; warm/CU ~ B 4 MB + partner X/M.
// B: per kt32, wave loads its 8 Wt frags straight to VGPRs, double-buffered (no LDS, no barrier).
// A: gelu(X)*mask per 128-k chunk in 2 x 16 KiB LDS; ONE barrier per chunk (32 total).
__global__ __launch_bounds__(512, 1)
void fused_gemm_kernel(const float* __restrict__ X, const int* __restrict__ Mask,
                       const u16* __restrict__ Wt, const float* __restrict__ Bias,
                       float* __restrict__ Out) {
  __shared__ __attribute__((aligned(16))) u16 Abuf[2][8192];  // 2 x 16 KiB

  const int tid  = threadIdx.x;
  const int lane = tid & 63;
  const int wv   = tid >> 6;          // 0..7
  const int wr   = wv >> 2;           // 0..1 : row half (32 rows)
  const int wc   = wv & 3;            // 0..3 : col quarter (128 cols)

  // ---- THE mapping change (R10 theory): same-stripe pair co-XCD ----
  const int bid = blockIdx.x;
  const int xcd = bid & 7;
  const int j   = bid >> 3;                        // 0..31
  const int it  = xcd * 16 + (j >> 1);             // row tile 0..127
  const int jh  = j & 1;                           // column half 0/1
  const int m0  = it * 64;
  const int n0  = jh * 512;

  // ---- X/mask register staging: 16 elems/thread per 128-k chunk (verified R5) ----
  const int xrow = tid >> 3;          // 0..63
  const int xe   = tid & 7;           // k-16-block 0..7
  const float* Xp = X    + (size_t)(m0 + xrow) * K_DIM + xe * 16;
  const int*   Mp = Mask + (size_t)(m0 + xrow) * K_DIM + xe * 16;
  float4 xs0, xs1, xs2, xs3;
  uint4  ms0, ms1, ms2, ms3;
  auto loadX = [&](int c) {
    const float* xp = Xp + c * 128;
    const int*   mp = Mp + c * 128;
    xs0 = *(const float4*)(xp + 0);
    xs1 = *(const float4*)(xp + 4);
    xs2 = *(const float4*)(xp + 8);
    xs3 = *(const float4*)(xp + 12);
    ms0 = *(const uint4*)(mp + 0);
    ms1 = *(const uint4*)(mp + 4);
    ms2 = *(const uint4*)(mp + 8);
    ms3 = *(const uint4*)(mp + 12);
  };
  // A frag layout per chunk: frag = kt(0..3)*4 + rf(0..3), 1 KiB each (lane = kq*16+row16).
  // thread covers k = xe*16..xe*16+15 of row xrow: kt = xe>>1, kq0 = (xe&1)*2. (verified R5)
  const u32 aOff = (u32)((((xe >> 1) * 4 + (xrow >> 4)) * 1024) +
                         ((xe & 1) * 2) * 256 + ((xrow & 15) * 16));
  auto writeA = [&](int buf) {
    u32 o0 = pack2(gelu_drop(xs0.x, ms0.x), gelu_drop(xs0.y, ms0.y));
    u32 o1 = pack2(gelu_drop(xs0.z, ms0.z), gelu_drop(xs0.w, ms0.w));
    u32 o2 = pack2(gelu_drop(xs1.x, ms1.x), gelu_drop(xs1.y, ms1.y));
    u32 o3 = pack2(gelu_drop(xs1.z, ms1.z), gelu_drop(xs1.w, ms1.w));
    u32 o4 = pack2(gelu_drop(xs2.x, ms2.x), gelu_drop(xs2.y, ms2.y));
    u32 o5 = pack2(gelu_drop(xs2.z, ms2.z), gelu_drop(xs2.w, ms2.w));
    u32 o6 = pack2(gelu_drop(xs3.x, ms3.x), gelu_drop(xs3.y, ms3.y));
    u32 o7 = pack2(gelu_drop(xs3.z, ms3.z), gelu_drop(xs3.w, ms3.w));
    char* base = (char*)Abuf[buf] + aOff;
    *(uint4*)(base)       = make_uint4(o0, o1, o2, o3);
    *(uint4*)(base + 256) = make_uint4(o4, o5, o6, o7);
  };

  // ---- B: direct global->reg, 8 frags/wave/kt (wave cols = n0 + wc*128), dbuf 2 deep ----
  const char* WtB = (const char*)Wt;
  const size_t bBase = (size_t)(jh * 32 + wc * 8) * 131072 + (size_t)lane * 16;
  half8 bs0[8], bs1[8];
  auto loadB = [&](int kt, half8 (&bs)[8]) {
#pragma unroll
    for (int jj = 0; jj < 8; ++jj)
      bs[jj] = *(const half8*)(WtB + bBase + (size_t)jj * 131072 + (size_t)kt * 1024);
  };

  f32x4 acc[2][8];
#pragma unroll
  for (int i = 0; i < 2; ++i)
#pragma unroll
    for (int jj = 0; jj < 8; ++jj)
      acc[i][jj] = (f32x4){0.f, 0.f, 0.f, 0.f};

  // one kt step: 2 A ds_reads + 16 MFMA (compiler inserts lgkmcnt/vmcnt waits)
  auto step = [&](int ab, int ktl, half8 (&bs)[8]) {
    half8 ar[2];
#pragma unroll
    for (int rf = 0; rf < 2; ++rf)
      ar[rf] = *(const half8*)((const char*)Abuf[ab] +
                               (size_t)(((ktl * 4 + wr * 2 + rf) * 1024) + lane * 16));
    __builtin_amdgcn_s_setprio(1);
#pragma unroll
    for (int rf = 0; rf < 2; ++rf)
#pragma unroll
      for (int jj = 0; jj < 8; ++jj)
        acc[rf][jj] = __builtin_amdgcn_mfma_f32_16x16x32_f16(ar[rf], bs[jj], acc[rf][jj], 0, 0, 0);
    __builtin_amdgcn_s_setprio(0);
  };

  // ---- prologue ----
  loadX(0);
  writeA(0);          // chunk 0 -> buf 0 (compiler waits on X loads)
  loadX(1);           // for chunk 1 (written at c=0)
  loadB(0, bs0);
  loadB(1, bs1);
  asm volatile("s_waitcnt lgkmcnt(0)" ::: "memory");
  __builtin_amdgcn_s_barrier();

#pragma unroll 1
  for (int c = 0; c < 32; ++c) {
    const int ab = c & 1;
    const int kt0 = c * 4;
    // chunk-boundary A work: gelu chunk c+1 into other buf; issue X for chunk c+2
    if (c + 1 < 32) writeA(ab ^ 1);
    if (c + 2 < 32) loadX(c + 2);
    // 4 kt steps; B sets alternate, refilled right after consumption (depth 2)
    step(ab, 0, bs0);
    if (kt0 + 2 < 128) loadB(kt0 + 2, bs0);
    step(ab, 1, bs1);
    if (kt0 + 3 < 128) loadB(kt0 + 3, bs1);
    step(ab, 2, bs0);
    if (kt0 + 4 < 128) loadB(kt0 + 4, bs0);
    step(ab, 3, bs1);
    if (kt0 + 5 < 128) loadB(kt0 + 5, bs1);
    // barrier: next chunk reads buf ab^1 (written above by all threads)
    if (c + 1 < 32) {
      asm volatile("s_waitcnt lgkmcnt(0)" ::: "memory");
      __builtin_amdgcn_s_barrier();
    }
  }

  // ---- epilogue: C/D layout col = lane&15, row = (lane>>4)*4 + reg [verified R3-R10] ----
  const int fr = lane & 15;
  const int rq = (lane >> 4) << 2;
#pragma unroll
  for (int rf = 0; rf < 2; ++rf) {
    const int row0 = m0 + wr * 32 + rf * 16 + rq;
#pragma unroll
    for (int jj = 0; jj < 8; ++jj) {
      const int col = n0 + wc * 128 + jj * 16 + fr;
      const float b = Bias[col];
#pragma unroll
      for (int r = 0; r < 4; ++r)
        Out[(size_t)(row0 + r) * N_DIM + col] = acc[rf][jj][r] + b;
    }
  }
}

// ---------------- fallback: verified R3 fused kernel (only if ws too small) ----------------
static constexpr int A_STRIDE = 40;

__global__ __launch_bounds__(256, 2)
void fused_fallback_kernel(const float* __restrict__ X, const float* __restrict__ W,
                           const float* __restrict__ Bias, const int* __restrict__ Mask,
                           float* __restrict__ Out) {
  __shared__ __attribute__((aligned(16))) _Float16 As[128 * A_STRIDE];
  __shared__ __attribute__((aligned(16))) _Float16 Bs[128 * 32];

  const int tid  = threadIdx.x;
  const int lane = tid & 63;
  const int wv   = tid >> 6;
  const int wr   = wv >> 1;
  const int wc   = wv & 1;
  const int bm = blockIdx.x & 63;
  const int bn = blockIdx.x >> 6;
  const int m0 = bm * 128;
  const int n0 = bn * 128;

  const int a_m = tid >> 1;
  const int a_k = (tid & 1) << 4;
  const float* xptr = X    + (size_t)(m0 + a_m) * K_DIM + a_k;
  const int*   mptr = Mask + (size_t)(m0 + a_m) * K_DIM + a_k;
  _Float16* a_lds = &As[a_m * A_STRIDE + a_k];

  const int i0 = tid, i1 = tid + 256;
  const float* wp0 = W + (size_t)(n0 + (i0 >> 2)) * K_DIM + ((i0 & 3) << 3);
  const float* wp1 = W + (size_t)(n0 + (i1 >> 2)) * K_DIM + ((i1 & 3) << 3);
  _Float16* bl0 = &Bs[i0 * 8];
  _Float16* bl1 = &Bs[i1 * 8];

  f32x4 acc[4][4];
#pragma unroll
  for (int i = 0; i < 4; ++i)
#pragma unroll
    for (int j = 0; j < 4; ++j)
      acc[i][j] = (f32x4){0.f, 0.f, 0.f, 0.f};

  float4 xf0 = *(const float4*)(xptr +  0);
  float4 xf1 = *(const float4*)(xptr +  4);
  float4 xf2 = *(const float4*)(xptr +  8);
  float4 xf3 = *(const float4*)(xptr + 12);
  uint4  mr0 = *(const uint4*)(mptr +  0);
  uint4  mr1 = *(const uint4*)(mptr +  4);
  uint4  mr2 = *(const uint4*)(mptr +  8);
  uint4  mr3 = *(const uint4*)(mptr + 12);
  float4 wf0 = *(const float4*)(wp0 + 0);
  float4 wf1 = *(const float4*)(wp0 + 4);
  float4 wf2 = *(const float4*)(wp1 + 0);
  float4 wf3 = *(const float4*)(wp1 + 4);

#pragma unroll 1
  for (int kt = 0; kt < 128; ++kt) {
    {
      float xs[16] = {xf0.x, xf0.y, xf0.z, xf0.w, xf1.x, xf1.y, xf1.z, xf1.w,
                      xf2.x, xf2.y, xf2.z, xf2.w, xf3.x, xf3.y, xf3.z, xf3.w};
      u32 mk[16]   = {mr0.x, mr0.y, mr0.z, mr0.w, mr1.x, mr1.y, mr1.z, mr1.w,
                      mr2.x, mr2.y, mr2.z, mr2.w, mr3.x, mr3.y, mr3.z, mr3.w};
      u32 ow[8];
#pragma unroll
      for (int e = 0; e < 8; ++e)
        ow[e] = pack2(gelu_drop(xs[2 * e], mk[2 * e]), gelu_drop(xs[2 * e + 1], mk[2 * e + 1]));
      ((uint4*)a_lds)[0] = make_uint4(ow[0], ow[1], ow[2], ow[3]);
      ((uint4*)a_lds)[1] = make_uint4(ow[4], ow[5], ow[6], ow[7]);
    }
    {
      *(uint4*)bl0 = make_uint4(pack2(wf0.x, wf0.y), pack2(wf0.z, wf0.w),
                                pack2(wf1.x, wf1.y), pack2(wf1.z, wf1.w));
      *(uint4*)bl1 = make_uint4(pack2(wf2.x, wf2.y), pack2(wf2.z, wf2.w),
                                pack2(wf3.x, wf3.y), pack2(wf3.z, wf3.w));
    }
    __syncthreads();

    if (kt + 1 < 128) {
      xptr += 32; mptr += 32; wp0 += 32; wp1 += 32;
      xf0 = *(const float4*)(xptr +  0);
      xf1 = *(const float4*)(xptr +  4);
      xf2 = *(const float4*)(xptr +  8);
      xf3 = *(const float4*)(xptr + 12);
      mr0 = *(const uint4*)(mptr +  0);
      mr1 = *(const uint4*)(mptr +  4);
      mr2 = *(const uint4*)(mptr +  8);
      mr3 = *(const uint4*)(mptr + 12);
      wf0 = *(const float4*)(wp0 + 0);
      wf1 = *(const float4*)(wp0 + 4);
      wf2 = *(const float4*)(wp1 + 0);
      wf3 = *(const float4*)(wp1 + 4);
    }

    {
      const int fr2 = lane & 15;
      const int fk2 = (lane >> 4) << 3;
      half8 ar[4], br[4];
#pragma unroll
      for (int i = 0; i < 4; ++i)
        ar[i] = *(const half8*)&As[(wr * 64 + i * 16 + fr2) * A_STRIDE + fk2];
#pragma unroll
      for (int j = 0; j < 4; ++j)
        br[j] = *(const half8*)&Bs[(wc * 64 + j * 16 + fr2) * 32 + fk2];
#pragma unroll
      for (int i = 0; i < 4; ++i)
#pragma unroll
        for (int j = 0; j < 4; ++j)
          acc[i][j] = __builtin_amdgcn_mfma_f32_16x16x32_f16(ar[i], br[j], acc[i][j], 0, 0, 0);
    }
    __syncthreads();
  }

  const int fr = lane & 15;
  const int rq = (lane >> 4) << 2;
  float bv[4];
#pragma unroll
  for (int j = 0; j < 4; ++j)
    bv[j] = Bias[n0 + wc * 64 + j * 16 + fr];
#pragma unroll
  for (int i = 0; i < 4; ++i) {
    const int row0 = m0 + wr * 64 + i * 16 + rq;
#pragma unroll
    for (int j = 0; j < 4; ++j) {
      const int col = n0 + wc * 64 + j * 16 + fr;
#pragma unroll
      for (int r = 0; r < 4; ++r)
        Out[(size_t)(row0 + r) * N_DIM + col] = acc[i][j][r] + bv[j];
    }
  }
}

extern "C" void kernel_launch(void* const* d_in, const int* in_sizes, int n_in,
                              void* d_out, int out_size, void* d_ws, size_t ws_size,
                              hipStream_t stream) {
  const float* X    = (const float*)d_in[0];   // x (8192x4096), fp16 canonicalized to f32
  const float* W    = (const float*)d_in[1];   // weight (1024x4096) f32, K-contiguous
  const float* Bias = (const float*)d_in[2];   // bias (1024) f32
  const int*   Mk   = (const int*)d_in[3];     // keep-mask int32 0/1
  float* Out = (float*)d_out;                  // y (8192x1024) f32

  if (ws_size >= WS_NEEDED) {
    u16* Wt = (u16*)d_ws;
    wpack_kernel<<<WPACK_BLOCKS, 256, 0, stream>>>(W, Wt);
    fused_gemm_kernel<<<256, 512, 0, stream>>>(X, Mk, Wt, Bias, Out);
  } else {
    fused_fallback_kernel<<<64 * 8, 256, 0, stream>>>(X, W, Bias, Mk, Out);
  }
}

// Round 12
// 369.799 us; speedup vs baseline: 1.0752x; 1.0151x over previous
//
#include <hip/hip_runtime.h>
#include <stdint.h>

typedef uint32_t u32;
typedef uint16_t u16;

static constexpr int M_DIM = 8192;
static constexpr int N_DIM = 1024;
static constexpr int K_DIM = 4096;

// Wt frag-major: [nb16(64)][kt32(128)] frags of 1 KiB; frag lane l = kq*16+row16 holds 16 B.
static constexpr size_t FRAG_U16 = 512;
static constexpr size_t WT_BYTES = 64ull * 128 * FRAG_U16 * 2;  // 8 MiB
static constexpr size_t WS_NEEDED = WT_BYTES;

typedef __attribute__((ext_vector_type(8))) _Float16 half8;  // MFMA A/B frag (4 VGPRs)
typedef __attribute__((ext_vector_type(4))) float f32x4;     // MFMA C/D frag

__device__ __forceinline__ u32 pack2(float a, float b) {
  union { _Float16 h[2]; u32 u; } p;
  p.h[0] = (_Float16)a;   // v_cvt_f16_f32, RNE
  p.h[1] = (_Float16)b;
  return p.u;
}

// GELU via Abramowitz-Stegun 7.1.26 erf (|err| <= 1.5e-7) + dropout keep-mask * 1/(1-0.1).
__device__ __forceinline__ float gelu_drop(float x, u32 keep) {
  float ax = fabsf(x);
  float z  = ax * 0.70710678f;
  float t  = __builtin_amdgcn_rcpf(fmaf(0.3275911f, z, 1.0f));
  float poly = fmaf(fmaf(fmaf(fmaf(1.061405429f, t, -1.453152027f),
                              t, 1.421413741f),
                         t, -0.284496736f),
                    t, 0.254829592f) * t;
  float e   = exp2f(z * z * -1.44269504f);    // exp(-z^2)
  float erf = fmaf(-poly, e, 1.0f);           // erf(|x|/sqrt(2)) in [0,1)
  float g   = 0.5f * x * (1.0f + copysignf(erf, x));
  return keep ? g * 1.1111112f : 0.0f;
}

// ---------------- W prepack (verified R3-R11): 17 MB f32 -> 8 MB fp16 frag-major ----------------
static constexpr int W_PAIRS = 64 * 64;          // nb(64) x kp(64)
static constexpr int WPACK_BLOCKS = W_PAIRS / 4; // 1024

__global__ __launch_bounds__(256)
void wpack_kernel(const float* __restrict__ W, u16* __restrict__ Wt) {
  const int l     = threadIdx.x & 63;
  const int pj    = blockIdx.x * 4 + (threadIdx.x >> 6);
  const int row16 = l & 15;
  const int kof   = (l >> 4) << 4;          // 0,16,32,48 within the 64-k pair
  const int fsub  = kof >> 5;               // 0 or 1
  const int q0    = (kof & 31) >> 3;        // 0 or 2

  const int nb = pj >> 6, kp = pj & 63;
  const float* wp = W + (size_t)(nb * 16 + row16) * K_DIM + kp * 64 + kof;
  float4 w0 = *(const float4*)(wp + 0);
  float4 w1 = *(const float4*)(wp + 4);
  float4 w2 = *(const float4*)(wp + 8);
  float4 w3 = *(const float4*)(wp + 12);
  const int f = kp * 2 + fsub;
  u16* dst = Wt + (size_t)(nb * 128 + f) * FRAG_U16 + (size_t)(row16 + 16 * q0) * 8;
  *(uint4*)(dst)       = make_uint4(pack2(w0.x, w0.y), pack2(w0.z, w0.w),
                                    pack2(w1.x, w1.y), pack2(w1.z, w1.w));
  *(uint4*)(dst + 128) = make_uint4(pack2(w2.x, w2.y), pack2(w2.z, w2.w),
                                    pack2(w3.x, w3.y), pack2(w3.z, w3.w));
}

// ---------------- fused GELU+dropout+GEMM: BM=64 x BN=512, no-dup B, swizzled A-LDS ----------------
// R11's mapping (same-stripe pair co-XCD) + two fixes from R11 counters:
//  (1) waves re-partitioned: 8 waves = 8 column-eighths (64 cols, all 4 row-frags each)
//      -> each B fragment loaded exactly ONCE per block: per-CU issue 10 MB -> 6 MB.
//  (2) A-LDS XOR swizzle phys = logical ^ ((kt<<4)|((kq>>1)<<6)): write phases become
//      bank-uniform (was ~8-way, 7.3M conflicts); reads stay conflict-free (XOR is
//      instruction-constant kt + a pure lane-bit permutation).
__global__ __launch_bounds__(512, 1)
void fused_gemm_kernel(const float* __restrict__ X, const int* __restrict__ Mask,
                       const u16* __restrict__ Wt, const float* __restrict__ Bias,
                       float* __restrict__ Out) {
  __shared__ __attribute__((aligned(16))) u16 Abuf[2][8192];  // 2 x 16 KiB

  const int tid  = threadIdx.x;
  const int lane = tid & 63;
  const int wv   = tid >> 6;          // 0..7 : column eighth (64 cols)

  // ---- mapping (verified R11): same-stripe pair co-XCD ----
  const int bid = blockIdx.x;
  const int xcd = bid & 7;
  const int j   = bid >> 3;                        // 0..31
  const int it  = xcd * 16 + (j >> 1);             // row tile 0..127
  const int jh  = j & 1;                           // column half 0/1
  const int m0  = it * 64;
  const int n0  = jh * 512;

  // ---- X/mask register staging: 16 elems/thread per 128-k chunk (verified R5/R11) ----
  const int xrow = tid >> 3;          // 0..63
  const int xe   = tid & 7;           // k-16-block 0..7
  const float* Xp = X    + (size_t)(m0 + xrow) * K_DIM + xe * 16;
  const int*   Mp = Mask + (size_t)(m0 + xrow) * K_DIM + xe * 16;
  float4 xs0, xs1, xs2, xs3;
  uint4  ms0, ms1, ms2, ms3;
  auto loadX = [&](int c) {
    const float* xp = Xp + c * 128;
    const int*   mp = Mp + c * 128;
    xs0 = *(const float4*)(xp + 0);
    xs1 = *(const float4*)(xp + 4);
    xs2 = *(const float4*)(xp + 8);
    xs3 = *(const float4*)(xp + 12);
    ms0 = *(const uint4*)(mp + 0);
    ms1 = *(const uint4*)(mp + 4);
    ms2 = *(const uint4*)(mp + 8);
    ms3 = *(const uint4*)(mp + 12);
  };
  // A chunk layout: 16 frags (frag = kt*4 + rf) of 1 KiB, slot (kq,r16) at kq*256+r16*16.
  // Physical addr = logical ^ ((kt<<4) | ((kq>>1)<<6)).  Write: kt=xe>>1, rf=xrow>>4,
  // kq0=(xe&1)*2 (both stores share kq>>1 = xe&1), r16=xrow&15.
  const u32 aBase = ((u32)(((xe >> 1) * 4 + (xrow >> 4)) * 1024) +
                     (u32)((xe & 1) * 512) + (u32)((xrow & 15) * 16)) ^
                    (((u32)(xe >> 1) << 4) | ((u32)(xe & 1) << 6));
  auto writeA = [&](int buf) {
    u32 o0 = pack2(gelu_drop(xs0.x, ms0.x), gelu_drop(xs0.y, ms0.y));
    u32 o1 = pack2(gelu_drop(xs0.z, ms0.z), gelu_drop(xs0.w, ms0.w));
    u32 o2 = pack2(gelu_drop(xs1.x, ms1.x), gelu_drop(xs1.y, ms1.y));
    u32 o3 = pack2(gelu_drop(xs1.z, ms1.z), gelu_drop(xs1.w, ms1.w));
    u32 o4 = pack2(gelu_drop(xs2.x, ms2.x), gelu_drop(xs2.y, ms2.y));
    u32 o5 = pack2(gelu_drop(xs2.z, ms2.z), gelu_drop(xs2.w, ms2.w));
    u32 o6 = pack2(gelu_drop(xs3.x, ms3.x), gelu_drop(xs3.y, ms3.y));
    u32 o7 = pack2(gelu_drop(xs3.z, ms3.z), gelu_drop(xs3.w, ms3.w));
    char* base = (char*)Abuf[buf] + aBase;
    *(uint4*)(base)       = make_uint4(o0, o1, o2, o3);
    *(uint4*)(base + 256) = make_uint4(o4, o5, o6, o7);   // kq0+1: same kq>>1, same swizzle
  };

  // ---- B: direct global->reg, 4 frags/wave/kt (wave cols = n0 + wv*64), dbuf 2 deep ----
  const char* WtB = (const char*)Wt;
  const size_t bBase = (size_t)(jh * 32 + wv * 4) * 131072 + (size_t)lane * 16;
  half8 bs0[4], bs1[4];
  auto loadB = [&](int kt, half8 (&bs)[4]) {
#pragma unroll
    for (int jj = 0; jj < 4; ++jj)
      bs[jj] = *(const half8*)(WtB + bBase + (size_t)jj * 131072 + (size_t)kt * 1024);
  };

  f32x4 acc[4][4];
#pragma unroll
  for (int i = 0; i < 4; ++i)
#pragma unroll
    for (int jj = 0; jj < 4; ++jj)
      acc[i][jj] = (f32x4){0.f, 0.f, 0.f, 0.f};

  // one kt step: 4 A ds_reads (swizzled) + 16 MFMA
  auto step = [&](int ab, int ktl, half8 (&bs)[4]) {
    const u32 rSwz = ((u32)ktl << 4) | (((u32)(lane >> 5) & 1u) << 6);
    half8 ar[4];
#pragma unroll
    for (int rf = 0; rf < 4; ++rf)
      ar[rf] = *(const half8*)((const char*)Abuf[ab] +
                               ((((u32)(ktl * 4 + rf) * 1024) + (u32)lane * 16) ^ rSwz));
    __builtin_amdgcn_s_setprio(1);
#pragma unroll
    for (int rf = 0; rf < 4; ++rf)
#pragma unroll
      for (int jj = 0; jj < 4; ++jj)
        acc[rf][jj] = __builtin_amdgcn_mfma_f32_16x16x32_f16(ar[rf], bs[jj], acc[rf][jj], 0, 0, 0);
    __builtin_amdgcn_s_setprio(0);
  };

  // ---- prologue ----
  loadX(0);
  writeA(0);          // chunk 0 -> buf 0 (compiler waits on X loads)
  loadX(1);           // for chunk 1 (written at c=0)
  loadB(0, bs0);
  loadB(1, bs1);
  asm volatile("s_waitcnt lgkmcnt(0)" ::: "memory");
  __builtin_amdgcn_s_barrier();

#pragma unroll 1
  for (int c = 0; c < 32; ++c) {
    const int ab = c & 1;
    const int kt0 = c * 4;
    // chunk-boundary A work: gelu chunk c+1 into other buf; issue X for chunk c+2
    if (c + 1 < 32) writeA(ab ^ 1);
    if (c + 2 < 32) loadX(c + 2);
    // 4 kt steps; B sets alternate, refilled right after consumption (depth 2)
    step(ab, 0, bs0);
    if (kt0 + 2 < 128) loadB(kt0 + 2, bs0);
    step(ab, 1, bs1);
    if (kt0 + 3 < 128) loadB(kt0 + 3, bs1);
    step(ab, 2, bs0);
    if (kt0 + 4 < 128) loadB(kt0 + 4, bs0);
    step(ab, 3, bs1);
    if (kt0 + 5 < 128) loadB(kt0 + 5, bs1);
    // barrier: next chunk reads buf ab^1 (written above by all threads)
    if (c + 1 < 32) {
      asm volatile("s_waitcnt lgkmcnt(0)" ::: "memory");
      __builtin_amdgcn_s_barrier();
    }
  }

  // ---- epilogue: C/D layout col = lane&15, row = (lane>>4)*4 + reg [verified R3-R11] ----
  const int fr = lane & 15;
  const int rq = (lane >> 4) << 2;
#pragma unroll
  for (int rf = 0; rf < 4; ++rf) {
    const int row0 = m0 + rf * 16 + rq;
#pragma unroll
    for (int jj = 0; jj < 4; ++jj) {
      const int col = n0 + wv * 64 + jj * 16 + fr;
      const float b = Bias[col];
#pragma unroll
      for (int r = 0; r < 4; ++r)
        Out[(size_t)(row0 + r) * N_DIM + col] = acc[rf][jj][r] + b;
    }
  }
}

// ---------------- fallback: verified R3 fused kernel (only if ws too small) ----------------
static constexpr int A_STRIDE = 40;

__global__ __launch_bounds__(256, 2)
void fused_fallback_kernel(const float* __restrict__ X, const float* __restrict__ W,
                           const float* __restrict__ Bias, const int* __restrict__ Mask,
                           float* __restrict__ Out) {
  __shared__ __attribute__((aligned(16))) _Float16 As[128 * A_STRIDE];
  __shared__ __attribute__((aligned(16))) _Float16 Bs[128 * 32];

  const int tid  = threadIdx.x;
  const int lane = tid & 63;
  const int wv   = tid >> 6;
  const int wr   = wv >> 1;
  const int wc   = wv & 1;
  const int bm = blockIdx.x & 63;
  const int bn = blockIdx.x >> 6;
  const int m0 = bm * 128;
  const int n0 = bn * 128;

  const int a_m = tid >> 1;
  const int a_k = (tid & 1) << 4;
  const float* xptr = X    + (size_t)(m0 + a_m) * K_DIM + a_k;
  const int*   mptr = Mask + (size_t)(m0 + a_m) * K_DIM + a_k;
  _Float16* a_lds = &As[a_m * A_STRIDE + a_k];

  const int i0 = tid, i1 = tid + 256;
  const float* wp0 = W + (size_t)(n0 + (i0 >> 2)) * K_DIM + ((i0 & 3) << 3);
  const float* wp1 = W + (size_t)(n0 + (i1 >> 2)) * K_DIM + ((i1 & 3) << 3);
  _Float16* bl0 = &Bs[i0 * 8];
  _Float16* bl1 = &Bs[i1 * 8];

  f32x4 acc[4][4];
#pragma unroll
  for (int i = 0; i < 4; ++i)
#pragma unroll
    for (int j = 0; j < 4; ++j)
      acc[i][j] = (f32x4){0.f, 0.f, 0.f, 0.f};

  float4 xf0 = *(const float4*)(xptr +  0);
  float4 xf1 = *(const float4*)(xptr +  4);
  float4 xf2 = *(const float4*)(xptr +  8);
  float4 xf3 = *(const float4*)(xptr + 12);
  uint4  mr0 = *(const uint4*)(mptr +  0);
  uint4  mr1 = *(const uint4*)(mptr +  4);
  uint4  mr2 = *(const uint4*)(mptr +  8);
  uint4  mr3 = *(const uint4*)(mptr + 12);
  float4 wf0 = *(const float4*)(wp0 + 0);
  float4 wf1 = *(const float4*)(wp0 + 4);
  float4 wf2 = *(const float4*)(wp1 + 0);
  float4 wf3 = *(const float4*)(wp1 + 4);

#pragma unroll 1
  for (int kt = 0; kt < 128; ++kt) {
    {
      float xs[16] = {xf0.x, xf0.y, xf0.z, xf0.w, xf1.x, xf1.y, xf1.z, xf1.w,
                      xf2.x, xf2.y, xf2.z, xf2.w, xf3.x, xf3.y, xf3.z, xf3.w};
      u32 mk[16]   = {mr0.x, mr0.y, mr0.z, mr0.w, mr1.x, mr1.y, mr1.z, mr1.w,
                      mr2.x, mr2.y, mr2.z, mr2.w, mr3.x, mr3.y, mr3.z, mr3.w};
      u32 ow[8];
#pragma unroll
      for (int e = 0; e < 8; ++e)
        ow[e] = pack2(gelu_drop(xs[2 * e], mk[2 * e]), gelu_drop(xs[2 * e + 1], mk[2 * e + 1]));
      ((uint4*)a_lds)[0] = make_uint4(ow[0], ow[1], ow[2], ow[3]);
      ((uint4*)a_lds)[1] = make_uint4(ow[4], ow[5], ow[6], ow[7]);
    }
    {
      *(uint4*)bl0 = make_uint4(pack2(wf0.x, wf0.y), pack2(wf0.z, wf0.w),
                                pack2(wf1.x, wf1.y), pack2(wf1.z, wf1.w));
      *(uint4*)bl1 = make_uint4(pack2(wf2.x, wf2.y), pack2(wf2.z, wf2.w),
                                pack2(wf3.x, wf3.y), pack2(wf3.z, wf3.w));
    }
    __syncthreads();

    if (kt + 1 < 128) {
      xptr += 32; mptr += 32; wp0 += 32; wp1 += 32;
      xf0 = *(const float4*)(xptr +  0);
      xf1 = *(const float4*)(xptr +  4);
      xf2 = *(const float4*)(xptr +  8);
      xf3 = *(const float4*)(xptr + 12);
      mr0 = *(const uint4*)(mptr +  0);
      mr1 = *(const uint4*)(mptr +  4);
      mr2 = *(const uint4*)(mptr +  8);
      mr3 = *(const uint4*)(mptr + 12);
      wf0 = *(const float4*)(wp0 + 0);
      wf1 = *(const float4*)(wp0 + 4);
      wf2 = *(const float4*)(wp1 + 0);
      wf3 = *(const float4*)(wp1 + 4);
    }

    {
      const int fr2 = lane & 15;
      const int fk2 = (lane >> 4) << 3;
      half8 ar[4], br[4];
#pragma unroll
      for (int i = 0; i < 4; ++i)
        ar[i] = *(const half8*)&As[(wr * 64 + i * 16 + fr2) * A_STRIDE + fk2];
#pragma unroll
      for (int j = 0; j < 4; ++j)
        br[j] = *(const half8*)&Bs[(wc * 64 + j * 16 + fr2) * 32 + fk2];
#pragma unroll
      for (int i = 0; i < 4; ++i)
#pragma unroll
        for (int j = 0; j < 4; ++j)
          acc[i][j] = __builtin_amdgcn_mfma_f32_16x16x32_f16(ar[i], br[j], acc[i][j], 0, 0, 0);
    }
    __syncthreads();
  }

  const int fr = lane & 15;
  const int rq = (lane >> 4) << 2;
  float bv[4];
#pragma unroll
  for (int j = 0; j < 4; ++j)
    bv[j] = Bias[n0 + wc * 64 + j * 16 + fr];
#pragma unroll
  for (int i = 0; i < 4; ++i) {
    const int row0 = m0 + wr * 64 + i * 16 + rq;
#pragma unroll
    for (int j = 0; j < 4; ++j) {
      const int col = n0 + wc * 64 + j * 16 + fr;
#pragma unroll
      for (int r = 0; r < 4; ++r)
        Out[(size_t)(row0 + r) * N_DIM + col] = acc[i][j][r] + bv[j];
    }
  }
}

extern "C" void kernel_launch(void* const* d_in, const int* in_sizes, int n_in,
                              void* d_out, int out_size, void* d_ws, size_t ws_size,
                              hipStream_t stream) {
  const float* X    = (const float*)d_in[0];   // x (8192x4096), fp16 canonicalized to f32
  const float* W    = (const float*)d_in[1];   // weight (1024x4096) f32, K-contiguous
  const float* Bias = (const float*)d_in[2];   // bias (1024) f32
  const int*   Mk   = (const int*)d_in[3];     // keep-mask int32 0/1
  float* Out = (float*)d_out;                  // y (8192x1024) f32

  if (ws_size >= WS_NEEDED) {
    u16* Wt = (u16*)d_ws;
    wpack_kernel<<<WPACK_BLOCKS, 256, 0, stream>>>(W, Wt);
    fused_gemm_kernel<<<256, 512, 0, stream>>>(X, Mk, Wt, Bias, Out);
  } else {
    fused_fallback_kernel<<<64 * 8, 256, 0, stream>>>(X, W, Bias, Mk, Out);
  }
}

// Round 13
// 346.243 us; speedup vs baseline: 1.1484x; 1.0680x over previous
//
#include <hip/hip_runtime.h>
#include <stdint.h>

typedef uint32_t u32;
typedef uint16_t u16;

static constexpr int M_DIM = 8192;
static constexpr int N_DIM = 1024;
static constexpr int K_DIM = 4096;

// Wt frag-major: [nb16(64)][kt32(128)] frags of 1 KiB; frag lane l = kq*16+row16 holds 16 B.
static constexpr size_t FRAG_U16 = 512;
static constexpr size_t WT_BYTES = 64ull * 128 * FRAG_U16 * 2;  // 8 MiB
static constexpr size_t WS_NEEDED = WT_BYTES;

typedef __attribute__((ext_vector_type(8))) _Float16 half8;  // MFMA A/B frag (4 VGPRs)
typedef __attribute__((ext_vector_type(4))) float f32x4;     // MFMA C/D frag

__device__ __forceinline__ u32 pack2(float a, float b) {
  union { _Float16 h[2]; u32 u; } p;
  p.h[0] = (_Float16)a;   // v_cvt_f16_f32, RNE
  p.h[1] = (_Float16)b;
  return p.u;
}

// GELU via Abramowitz-Stegun 7.1.26 erf (|err| <= 1.5e-7) + dropout keep-mask * 1/(1-0.1).
__device__ __forceinline__ float gelu_drop(float x, u32 keep) {
  float ax = fabsf(x);
  float z  = ax * 0.70710678f;
  float t  = __builtin_amdgcn_rcpf(fmaf(0.3275911f, z, 1.0f));
  float poly = fmaf(fmaf(fmaf(fmaf(1.061405429f, t, -1.453152027f),
                              t, 1.421413741f),
                         t, -0.284496736f),
                    t, 0.254829592f) * t;
  float e   = exp2f(z * z * -1.44269504f);    // exp(-z^2)
  float erf = fmaf(-poly, e, 1.0f);           // erf(|x|/sqrt(2)) in [0,1)
  float g   = 0.5f * x * (1.0f + copysignf(erf, x));
  return keep ? g * 1.1111112f : 0.0f;
}

// ---------------- W prepack (verified R3-R12): 17 MB f32 -> 8 MB fp16 frag-major ----------------
static constexpr int W_PAIRS = 64 * 64;          // nb(64) x kp(64)
static constexpr int WPACK_BLOCKS = W_PAIRS / 4; // 1024

__global__ __launch_bounds__(256)
void wpack_kernel(const float* __restrict__ W, u16* __restrict__ Wt) {
  const int l     = threadIdx.x & 63;
  const int pj    = blockIdx.x * 4 + (threadIdx.x >> 6);
  const int row16 = l & 15;
  const int kof   = (l >> 4) << 4;          // 0,16,32,48 within the 64-k pair
  const int fsub  = kof >> 5;               // 0 or 1
  const int q0    = (kof & 31) >> 3;        // 0 or 2

  const int nb = pj >> 6, kp = pj & 63;
  const float* wp = W + (size_t)(nb * 16 + row16) * K_DIM + kp * 64 + kof;
  float4 w0 = *(const float4*)(wp + 0);
  float4 w1 = *(const float4*)(wp + 4);
  float4 w2 = *(const float4*)(wp + 8);
  float4 w3 = *(const float4*)(wp + 12);
  const int f = kp * 2 + fsub;
  u16* dst = Wt + (size_t)(nb * 128 + f) * FRAG_U16 + (size_t)(row16 + 16 * q0) * 8;
  *(uint4*)(dst)       = make_uint4(pack2(w0.x, w0.y), pack2(w0.z, w0.w),
                                    pack2(w1.x, w1.y), pack2(w1.z, w1.w));
  *(uint4*)(dst + 128) = make_uint4(pack2(w2.x, w2.y), pack2(w2.z, w2.w),
                                    pack2(w3.x, w3.y), pack2(w3.z, w3.w));
}

// ---------------- fused GELU+dropout+GEMM: BM=64 x BN=512, 16 waves (4/SIMD) ----------------
// R12's verified machinery (mapping, no-dup B, A-swizzle, epilogue) with ONE change: TLP.
// 1024 threads = 16 waves = 4 waves/SIMD (was 2): doubles latency coverage for the B
// prefetch and interleaves gelu-VALU/MFMA issue across more waves. Byte counts unchanged
// (6 MB/CU: B 4 MB once + X/M 2 MB). Wave wv owns 32 cols (2 B-frags); acc = 4x2 frags.
__global__ __launch_bounds__(1024, 4)
void fused_gemm_kernel(const float* __restrict__ X, const int* __restrict__ Mask,
                       const u16* __restrict__ Wt, const float* __restrict__ Bias,
                       float* __restrict__ Out) {
  __shared__ __attribute__((aligned(16))) u16 Abuf[2][8192];  // 2 x 16 KiB

  const int tid  = threadIdx.x;
  const int lane = tid & 63;
  const int wv   = tid >> 6;          // 0..15 : column sixteenth (32 cols)

  // ---- mapping (verified R11/R12): same-stripe pair co-XCD ----
  const int bid = blockIdx.x;
  const int xcd = bid & 7;
  const int j   = bid >> 3;                        // 0..31
  const int it  = xcd * 16 + (j >> 1);             // row tile 0..127
  const int jh  = j & 1;                           // column half 0/1
  const int m0  = it * 64;
  const int n0  = jh * 512;

  // ---- X/mask register staging: 8 elems/thread per 128-k chunk ----
  const int xrow = tid >> 4;          // 0..63
  const int xe8  = tid & 15;          // k-octet 0..15
  const float* Xp = X    + (size_t)(m0 + xrow) * K_DIM + xe8 * 8;
  const int*   Mp = Mask + (size_t)(m0 + xrow) * K_DIM + xe8 * 8;
  float4 xs0, xs1;
  uint4  ms0, ms1;
  auto loadX = [&](int c) {
    const float* xp = Xp + c * 128;
    const int*   mp = Mp + c * 128;
    xs0 = *(const float4*)(xp + 0);
    xs1 = *(const float4*)(xp + 4);
    ms0 = *(const uint4*)(mp + 0);
    ms1 = *(const uint4*)(mp + 4);
  };
  // A chunk layout (verified R12): frag = kt*4+rf (1 KiB), slot (kq,r16) at kq*256+r16*16;
  // phys = logical ^ ((kt<<4)|((kq>>1)<<6)). Thread: kt=xe8>>2, kq=xe8&3 (one 16-B slot).
  const u32 kt_w = (u32)(xe8 >> 2), kq_w = (u32)(xe8 & 3);
  const u32 aBase = (((kt_w * 4 + (u32)(xrow >> 4)) * 1024) + kq_w * 256 +
                     (u32)(xrow & 15) * 16) ^
                    ((kt_w << 4) | ((kq_w >> 1) << 6));
  auto writeA = [&](int buf) {
    u32 o0 = pack2(gelu_drop(xs0.x, ms0.x), gelu_drop(xs0.y, ms0.y));
    u32 o1 = pack2(gelu_drop(xs0.z, ms0.z), gelu_drop(xs0.w, ms0.w));
    u32 o2 = pack2(gelu_drop(xs1.x, ms1.x), gelu_drop(xs1.y, ms1.y));
    u32 o3 = pack2(gelu_drop(xs1.z, ms1.z), gelu_drop(xs1.w, ms1.w));
    *(uint4*)((char*)Abuf[buf] + aBase) = make_uint4(o0, o1, o2, o3);
  };

  // ---- B: direct global->reg, 2 frags/wave/kt (wave cols = n0 + wv*32), dbuf 2 deep ----
  const char* WtB = (const char*)Wt;
  const size_t bBase = (size_t)(jh * 32 + wv * 2) * 131072 + (size_t)lane * 16;
  half8 bs0[2], bs1[2];
  auto loadB = [&](int kt, half8 (&bs)[2]) {
#pragma unroll
    for (int jj = 0; jj < 2; ++jj)
      bs[jj] = *(const half8*)(WtB + bBase + (size_t)jj * 131072 + (size_t)kt * 1024);
  };

  f32x4 acc[4][2];
#pragma unroll
  for (int i = 0; i < 4; ++i)
#pragma unroll
    for (int jj = 0; jj < 2; ++jj)
      acc[i][jj] = (f32x4){0.f, 0.f, 0.f, 0.f};

  // one kt step: 4 A ds_reads (swizzled, verified R12) + 8 MFMA
  auto step = [&](int ab, int ktl, half8 (&bs)[2]) {
    const u32 rSwz = ((u32)ktl << 4) | (((u32)(lane >> 5) & 1u) << 6);
    half8 ar[4];
#pragma unroll
    for (int rf = 0; rf < 4; ++rf)
      ar[rf] = *(const half8*)((const char*)Abuf[ab] +
                               ((((u32)(ktl * 4 + rf) * 1024) + (u32)lane * 16) ^ rSwz));
    __builtin_amdgcn_s_setprio(1);
#pragma unroll
    for (int rf = 0; rf < 4; ++rf)
#pragma unroll
      for (int jj = 0; jj < 2; ++jj)
        acc[rf][jj] = __builtin_amdgcn_mfma_f32_16x16x32_f16(ar[rf], bs[jj], acc[rf][jj], 0, 0, 0);
    __builtin_amdgcn_s_setprio(0);
  };

  // ---- prologue ----
  loadX(0);
  writeA(0);          // chunk 0 -> buf 0 (compiler waits on X loads)
  loadX(1);           // for chunk 1 (written at c=0)
  loadB(0, bs0);
  loadB(1, bs1);
  asm volatile("s_waitcnt lgkmcnt(0)" ::: "memory");
  __builtin_amdgcn_s_barrier();

#pragma unroll 1
  for (int c = 0; c < 32; ++c) {
    const int ab = c & 1;
    const int kt0 = c * 4;
    // chunk-boundary A work: gelu chunk c+1 into other buf; issue X for chunk c+2
    if (c + 1 < 32) writeA(ab ^ 1);
    if (c + 2 < 32) loadX(c + 2);
    // 4 kt steps; B sets alternate, refilled right after consumption (depth 2)
    step(ab, 0, bs0);
    if (kt0 + 2 < 128) loadB(kt0 + 2, bs0);
    step(ab, 1, bs1);
    if (kt0 + 3 < 128) loadB(kt0 + 3, bs1);
    step(ab, 2, bs0);
    if (kt0 + 4 < 128) loadB(kt0 + 4, bs0);
    step(ab, 3, bs1);
    if (kt0 + 5 < 128) loadB(kt0 + 5, bs1);
    // barrier: next chunk reads buf ab^1 (written above by all threads)
    if (c + 1 < 32) {
      asm volatile("s_waitcnt lgkmcnt(0)" ::: "memory");
      __builtin_amdgcn_s_barrier();
    }
  }

  // ---- epilogue: C/D layout col = lane&15, row = (lane>>4)*4 + reg [verified R3-R12] ----
  const int fr = lane & 15;
  const int rq = (lane >> 4) << 2;
#pragma unroll
  for (int rf = 0; rf < 4; ++rf) {
    const int row0 = m0 + rf * 16 + rq;
#pragma unroll
    for (int jj = 0; jj < 2; ++jj) {
      const int col = n0 + wv * 32 + jj * 16 + fr;
      const float b = Bias[col];
#pragma unroll
      for (int r = 0; r < 4; ++r)
        Out[(size_t)(row0 + r) * N_DIM + col] = acc[rf][jj][r] + b;
    }
  }
}

// ---------------- fallback: verified R3 fused kernel (only if ws too small) ----------------
static constexpr int A_STRIDE = 40;

__global__ __launch_bounds__(256, 2)
void fused_fallback_kernel(const float* __restrict__ X, const float* __restrict__ W,
                           const float* __restrict__ Bias, const int* __restrict__ Mask,
                           float* __restrict__ Out) {
  __shared__ __attribute__((aligned(16))) _Float16 As[128 * A_STRIDE];
  __shared__ __attribute__((aligned(16))) _Float16 Bs[128 * 32];

  const int tid  = threadIdx.x;
  const int lane = tid & 63;
  const int wv   = tid >> 6;
  const int wr   = wv >> 1;
  const int wc   = wv & 1;
  const int bm = blockIdx.x & 63;
  const int bn = blockIdx.x >> 6;
  const int m0 = bm * 128;
  const int n0 = bn * 128;

  const int a_m = tid >> 1;
  const int a_k = (tid & 1) << 4;
  const float* xptr = X    + (size_t)(m0 + a_m) * K_DIM + a_k;
  const int*   mptr = Mask + (size_t)(m0 + a_m) * K_DIM + a_k;
  _Float16* a_lds = &As[a_m * A_STRIDE + a_k];

  const int i0 = tid, i1 = tid + 256;
  const float* wp0 = W + (size_t)(n0 + (i0 >> 2)) * K_DIM + ((i0 & 3) << 3);
  const float* wp1 = W + (size_t)(n0 + (i1 >> 2)) * K_DIM + ((i1 & 3) << 3);
  _Float16* bl0 = &Bs[i0 * 8];
  _Float16* bl1 = &Bs[i1 * 8];

  f32x4 acc[4][4];
#pragma unroll
  for (int i = 0; i < 4; ++i)
#pragma unroll
    for (int j = 0; j < 4; ++j)
      acc[i][j] = (f32x4){0.f, 0.f, 0.f, 0.f};

  float4 xf0 = *(const float4*)(xptr +  0);
  float4 xf1 = *(const float4*)(xptr +  4);
  float4 xf2 = *(const float4*)(xptr +  8);
  float4 xf3 = *(const float4*)(xptr + 12);
  uint4  mr0 = *(const uint4*)(mptr +  0);
  uint4  mr1 = *(const uint4*)(mptr +  4);
  uint4  mr2 = *(const uint4*)(mptr +  8);
  uint4  mr3 = *(const uint4*)(mptr + 12);
  float4 wf0 = *(const float4*)(wp0 + 0);
  float4 wf1 = *(const float4*)(wp0 + 4);
  float4 wf2 = *(const float4*)(wp1 + 0);
  float4 wf3 = *(const float4*)(wp1 + 4);

#pragma unroll 1
  for (int kt = 0; kt < 128; ++kt) {
    {
      float xs[16] = {xf0.x, xf0.y, xf0.z, xf0.w, xf1.x, xf1.y, xf1.z, xf1.w,
                      xf2.x, xf2.y, xf2.z, xf2.w, xf3.x, xf3.y, xf3.z, xf3.w};
      u32 mk[16]   = {mr0.x, mr0.y, mr0.z, mr0.w, mr1.x, mr1.y, mr1.z, mr1.w,
                      mr2.x, mr2.y, mr2.z, mr2.w, mr3.x, mr3.y, mr3.z, mr3.w};
      u32 ow[8];
#pragma unroll
      for (int e = 0; e < 8; ++e)
        ow[e] = pack2(gelu_drop(xs[2 * e], mk[2 * e]), gelu_drop(xs[2 * e + 1], mk[2 * e + 1]));
      ((uint4*)a_lds)[0] = make_uint4(ow[0], ow[1], ow[2], ow[3]);
      ((uint4*)a_lds)[1] = make_uint4(ow[4], ow[5], ow[6], ow[7]);
    }
    {
      *(uint4*)bl0 = make_uint4(pack2(wf0.x, wf0.y), pack2(wf0.z, wf0.w),
                                pack2(wf1.x, wf1.y), pack2(wf1.z, wf1.w));
      *(uint4*)bl1 = make_uint4(pack2(wf2.x, wf2.y), pack2(wf2.z, wf2.w),
                                pack2(wf3.x, wf3.y), pack2(wf3.z, wf3.w));
    }
    __syncthreads();

    if (kt + 1 < 128) {
      xptr += 32; mptr += 32; wp0 += 32; wp1 += 32;
      xf0 = *(const float4*)(xptr +  0);
      xf1 = *(const float4*)(xptr +  4);
      xf2 = *(const float4*)(xptr +  8);
      xf3 = *(const float4*)(xptr + 12);
      mr0 = *(const uint4*)(mptr +  0);
      mr1 = *(const uint4*)(mptr +  4);
      mr2 = *(const uint4*)(mptr +  8);
      mr3 = *(const uint4*)(mptr + 12);
      wf0 = *(const float4*)(wp0 + 0);
      wf1 = *(const float4*)(wp0 + 4);
      wf2 = *(const float4*)(wp1 + 0);
      wf3 = *(const float4*)(wp1 + 4);
    }

    {
      const int fr2 = lane & 15;
      const int fk2 = (lane >> 4) << 3;
      half8 ar[4], br[4];
#pragma unroll
      for (int i = 0; i < 4; ++i)
        ar[i] = *(const half8*)&As[(wr * 64 + i * 16 + fr2) * A_STRIDE + fk2];
#pragma unroll
      for (int j = 0; j < 4; ++j)
        br[j] = *(const half8*)&Bs[(wc * 64 + j * 16 + fr2) * 32 + fk2];
#pragma unroll
      for (int i = 0; i < 4; ++i)
#pragma unroll
        for (int j = 0; j < 4; ++j)
          acc[i][j] = __builtin_amdgcn_mfma_f32_16x16x32_f16(ar[i], br[j], acc[i][j], 0, 0, 0);
    }
    __syncthreads();
  }

  const int fr = lane & 15;
  const int rq = (lane >> 4) << 2;
  float bv[4];
#pragma unroll
  for (int j = 0; j < 4; ++j)
    bv[j] = Bias[n0 + wc * 64 + j * 16 + fr];
#pragma unroll
  for (int i = 0; i < 4; ++i) {
    const int row0 = m0 + wr * 64 + i * 16 + rq;
#pragma unroll
    for (int j = 0; j < 4; ++j) {
      const int col = n0 + wc * 64 + j * 16 + fr;
#pragma unroll
      for (int r = 0; r < 4; ++r)
        Out[(size_t)(row0 + r) * N_DIM + col] = acc[i][j][r] + bv[j];
    }
  }
}

extern "C" void kernel_launch(void* const* d_in, const int* in_sizes, int n_in,
                              void* d_out, int out_size, void* d_ws, size_t ws_size,
                              hipStream_t stream) {
  const float* X    = (const float*)d_in[0];   // x (8192x4096), fp16 canonicalized to f32
  const float* W    = (const float*)d_in[1];   // weight (1024x4096) f32, K-contiguous
  const float* Bias = (const float*)d_in[2];   // bias (1024) f32
  const int*   Mk   = (const int*)d_in[3];     // keep-mask int32 0/1
  float* Out = (float*)d_out;                  // y (8192x1024) f32

  if (ws_size >= WS_NEEDED) {
    u16* Wt = (u16*)d_ws;
    wpack_kernel<<<WPACK_BLOCKS, 256, 0, stream>>>(W, Wt);
    fused_gemm_kernel<<<256, 1024, 0, stream>>>(X, Mk, Wt, Bias, Out);
  } else {
    fused_fallback_kernel<<<64 * 8, 256, 0, stream>>>(X, W, Bias, Mk, Out);
  }
}